// Round 4
// baseline (56.924 us; speedup 1.0000x reference)
//
#include <hip/hip_runtime.h>

#define NMAPS 8
#define BATCH 32
#define DLEN  150528              // 3*224*224
#define D2    (DLEN / 2)          // 75264 float2 per (map, batch) row
#define NPAIR 36                  // i<=j pairs incl diagonal (diag = norm^2)
#define CHUNKS 32                 // blocks per batch element
#define TPB   512                 // 8 waves/block
#define REG2  (D2 / CHUNKS)       // 2352 float2, contiguous region per block
#define FULL_ITERS (REG2 / TPB)   // 4
#define TAIL  (REG2 - FULL_ITERS * TPB)  // 304

__device__ __forceinline__ void gram_step(const float2* __restrict__ base,
                                          size_t strideI, size_t j,
                                          float acc[NPAIR]) {
    float2 v[NMAPS];
#pragma unroll
    for (int i = 0; i < NMAPS; ++i) v[i] = base[(size_t)i * strideI + j];
    int k = 0;
#pragma unroll
    for (int i = 0; i < NMAPS; ++i) {
#pragma unroll
        for (int jj = i; jj < NMAPS; ++jj) {
            acc[k] += v[i].x * v[jj].x + v[i].y * v[jj].y;
            ++k;
        }
    }
}

// Kernel 1: 36 unique pairwise dots per batch element, single pass.
// Low-VGPR / high-TLP variant: float2 loads, 8 waves/SIMD forced.
__global__ __launch_bounds__(TPB, 8) void gram_kernel(const float* __restrict__ xf,
                                                      float* __restrict__ partial) {
    const int b     = blockIdx.x;    // 0..31
    const int chunk = blockIdx.y;    // 0..31
    const int tid   = threadIdx.x;

    const float2* xb = reinterpret_cast<const float2*>(xf) + (size_t)b * D2;
    const size_t strideI = (size_t)BATCH * D2;   // float2 stride between maps

    float acc[NPAIR];
#pragma unroll
    for (int k = 0; k < NPAIR; ++k) acc[k] = 0.0f;

    const size_t j0 = (size_t)chunk * REG2 + tid;   // contiguous region

#pragma unroll 1
    for (int it = 0; it < FULL_ITERS; ++it)
        gram_step(xb, strideI, j0 + (size_t)it * TPB, acc);
    if (tid < TAIL)
        gram_step(xb, strideI, j0 + (size_t)FULL_ITERS * TPB, acc);

    // wave shuffle reduce, then cross-wave LDS reduce (8 waves)
    const int lane = tid & 63;
    const int wave = tid >> 6;
    __shared__ float red[TPB / 64][NPAIR];
#pragma unroll
    for (int k = 0; k < NPAIR; ++k) {
        float s = acc[k];
#pragma unroll
        for (int off = 32; off > 0; off >>= 1) s += __shfl_down(s, off, 64);
        if (lane == 0) red[wave][k] = s;
    }
    __syncthreads();
    if (tid < NPAIR) {
        float t = 0.0f;
#pragma unroll
        for (int w = 0; w < TPB / 64; ++w) t += red[w][tid];
        // layout: partial[(b*36+k)*CHUNKS + chunk] -> finalize reads float4
        partial[((size_t)b * NPAIR + tid) * CHUNKS + chunk] = t;
    }
}

// Kernel 2: sum partials over chunks, then cosine epilogue. One block.
__global__ __launch_bounds__(256) void finalize_kernel(const float* __restrict__ partial,
                                                       float* __restrict__ out) {
    const int tid = threadIdx.x;
    __shared__ float dots_s[BATCH * NPAIR];   // [b][k]
    __shared__ float norms[BATCH][NMAPS];

    for (int item = tid; item < BATCH * NPAIR; item += 256) {
        const float4* p = reinterpret_cast<const float4*>(partial + (size_t)item * CHUNKS);
        float s = 0.0f;
#pragma unroll
        for (int c = 0; c < CHUNKS / 4; ++c) {
            float4 t = p[c];
            s += t.x + t.y + t.z + t.w;
        }
        dots_s[item] = s;
    }
    __syncthreads();
    {
        int bb = tid >> 3, i = tid & 7;             // 256 = 32*8
        int diag = 8 * i - (i * (i - 1)) / 2;
        norms[bb][i] = sqrtf(dots_s[bb * NPAIR + diag]);
    }
    __syncthreads();

    float sum = 0.0f;
    for (int item = tid; item < 28 * BATCH; item += 256) {
        int p = item >> 5;   // pair 0..27
        int bb = item & 31;
        int i = 0, rem = p;
        while (rem >= 7 - i) { rem -= 7 - i; ++i; }
        int j = i + 1 + rem;
        int k = 8 * i - (i * (i - 1)) / 2 + (j - i);
        float d   = fabsf(dots_s[bb * NPAIR + k]);
        float den = fmaxf(norms[bb][i] * norms[bb][j], 1e-8f);
        sum += d / den;
    }

    const int lane = tid & 63, wave = tid >> 6;
    __shared__ float red2[4];
#pragma unroll
    for (int off = 32; off > 0; off >>= 1) sum += __shfl_down(sum, off, 64);
    if (lane == 0) red2[wave] = sum;
    __syncthreads();
    if (tid == 0)
        out[0] = (red2[0] + red2[1] + red2[2] + red2[3]) / (28.0f * BATCH);
}

extern "C" void kernel_launch(void* const* d_in, const int* in_sizes, int n_in,
                              void* d_out, int out_size, void* d_ws, size_t ws_size,
                              hipStream_t stream) {
    const float* x       = (const float*)d_in[0];
    float*       out     = (float*)d_out;
    float*       partial = (float*)d_ws;   // BATCH*NPAIR*CHUNKS floats = 147 KB

    dim3 grid(BATCH, CHUNKS);
    gram_kernel<<<grid, TPB, 0, stream>>>(x, partial);
    finalize_kernel<<<1, 256, 0, stream>>>(partial, out);
}

// Round 5
// 52.066 us; speedup vs baseline: 1.0933x; 1.0933x over previous
//
#include <hip/hip_runtime.h>
#include <stdint.h>

#define NMAPS 8
#define BATCH 32
#define DLEN  150528              // 3*224*224
#define D4    (DLEN / 4)          // 37632 float4 per (map, batch) row
#define NPAIR 36                  // i<=j pairs incl diagonal (diag = norm^2)
#define NC    49                  // chunks per batch row
#define TILES_PER_BLOCK 3         // 49 * 3 = 147 tiles of 256 float4 = 37632
#define TILE4 256                 // float4 per map per tile (4 KB/map)
#define TPB   256
#define NITEMS (BATCH * NPAIR)    // 1152

// async global->LDS, 16B per lane, lane i lands at lds_base + i*16
__device__ __forceinline__ void stage16(const float4* g, float4* l) {
    __builtin_amdgcn_global_load_lds(
        (const __attribute__((address_space(1))) uint32_t*)g,
        (__attribute__((address_space(3))) uint32_t*)l,
        16, 0, 0);
}

// Kernel 1: per (b, chunk) block, stage 8-map tiles to LDS (map-major 4KB
// contiguous bursts), compute 36 pairwise dot partials from LDS.
__global__ __launch_bounds__(TPB) void gram_kernel(const float* __restrict__ xf,
                                                   float* __restrict__ partial) {
    const int b    = blockIdx.x;    // 0..31
    const int c    = blockIdx.y;    // 0..48
    const int tid  = threadIdx.x;
    const int lane = tid & 63;
    const int w    = tid >> 6;      // wave 0..3

    __shared__ float4 buf[NMAPS * TILE4];   // 32 KB

    const float4* x4 = reinterpret_cast<const float4*>(xf);
    const size_t strideI = (size_t)BATCH * D4;       // float4 stride between maps
    const float4* xb = x4 + (size_t)b * D4;

    float acc[NPAIR];
#pragma unroll
    for (int k = 0; k < NPAIR; ++k) acc[k] = 0.0f;

#pragma unroll 1
    for (int t = 0; t < TILES_PER_BLOCK; ++t) {
        const size_t j0 = (size_t)(c + t * NC) * TILE4;
        // stage: wave w loads 64-float4 sub-segment w of each map
#pragma unroll
        for (int m = 0; m < NMAPS; ++m) {
            stage16(xb + (size_t)m * strideI + j0 + (size_t)w * 64 + lane,
                    &buf[m * TILE4 + w * 64]);
        }
        __syncthreads();   // drains vmcnt(0): tile present

        float4 v[NMAPS];
#pragma unroll
        for (int m = 0; m < NMAPS; ++m) v[m] = buf[m * TILE4 + tid];
        int k = 0;
#pragma unroll
        for (int i = 0; i < NMAPS; ++i) {
#pragma unroll
            for (int j = i; j < NMAPS; ++j) {
                acc[k] += v[i].x * v[j].x + v[i].y * v[j].y +
                          v[i].z * v[j].z + v[i].w * v[j].w;
                ++k;
            }
        }
        __syncthreads();   // all waves done reading before next overwrite
    }

    // wave shuffle reduce, then cross-wave LDS reduce
    __shared__ float red[TPB / 64][NPAIR];
#pragma unroll
    for (int k = 0; k < NPAIR; ++k) {
        float s = acc[k];
#pragma unroll
        for (int off = 32; off > 0; off >>= 1) s += __shfl_down(s, off, 64);
        if (lane == 0) red[w][k] = s;
    }
    __syncthreads();
    if (tid < NPAIR) {
        float t = red[0][tid] + red[1][tid] + red[2][tid] + red[3][tid];
        // layout: partial[c*1152 + b*36 + k]  (finalize reads coalesced)
        partial[(size_t)c * NITEMS + b * NPAIR + tid] = t;
    }
}

// Kernel 2: sum partials over the 49 chunks, then cosine epilogue. One block.
__global__ __launch_bounds__(256) void finalize_kernel(const float* __restrict__ partial,
                                                       float* __restrict__ out) {
    const int tid = threadIdx.x;
    __shared__ float dots_s[NITEMS];          // [b][k]
    __shared__ float norms[BATCH][NMAPS];

    for (int item = tid; item < NITEMS; item += 256) {
        float s = 0.0f;
#pragma unroll
        for (int c = 0; c < NC; ++c) s += partial[(size_t)c * NITEMS + item];
        dots_s[item] = s;
    }
    __syncthreads();
    {
        int bb = tid >> 3, i = tid & 7;             // 256 = 32*8
        int diag = 8 * i - (i * (i - 1)) / 2;
        norms[bb][i] = sqrtf(dots_s[bb * NPAIR + diag]);
    }
    __syncthreads();

    float sum = 0.0f;
    for (int item = tid; item < 28 * BATCH; item += 256) {
        int p = item >> 5;   // pair 0..27
        int bb = item & 31;
        int i = 0, rem = p;
        while (rem >= 7 - i) { rem -= 7 - i; ++i; }
        int j = i + 1 + rem;
        int k = 8 * i - (i * (i - 1)) / 2 + (j - i);
        float d   = fabsf(dots_s[bb * NPAIR + k]);
        float den = fmaxf(norms[bb][i] * norms[bb][j], 1e-8f);
        sum += d / den;
    }

    const int lane = tid & 63, wave = tid >> 6;
    __shared__ float red2[4];
#pragma unroll
    for (int off = 32; off > 0; off >>= 1) sum += __shfl_down(sum, off, 64);
    if (lane == 0) red2[wave] = sum;
    __syncthreads();
    if (tid == 0)
        out[0] = (red2[0] + red2[1] + red2[2] + red2[3]) / (28.0f * BATCH);
}

extern "C" void kernel_launch(void* const* d_in, const int* in_sizes, int n_in,
                              void* d_out, int out_size, void* d_ws, size_t ws_size,
                              hipStream_t stream) {
    const float* x       = (const float*)d_in[0];
    float*       out     = (float*)d_out;
    float*       partial = (float*)d_ws;   // NC*NITEMS floats = 226 KB

    dim3 grid(BATCH, NC);
    gram_kernel<<<grid, TPB, 0, stream>>>(x, partial);
    finalize_kernel<<<1, 256, 0, stream>>>(partial, out);
}

// Round 7
// 40.051 us; speedup vs baseline: 1.4213x; 1.3000x over previous
//
#include <hip/hip_runtime.h>

#define NMAPS 8
#define BATCH 32
#define DLEN  150528              // 3*224*224
#define D4    (DLEN / 4)          // 37632 float4 per (map, batch) row
#define NPAIR 36                  // i<=j pairs incl diagonal (diag = norm^2)
#define CHUNKS 32                 // blocks per batch element
#define TPB   256
#define JSTRIDE (CHUNKS * TPB)    // 8192 float4

typedef float floatx4 __attribute__((ext_vector_type(4)));

// Kernel 1: 36 unique pairwise dots per batch element, single pass over the
// 154 MB input. Non-temporal float4 loads (streaming, no cache allocation).
__global__ __launch_bounds__(TPB) void gram_kernel(const float* __restrict__ xf,
                                                   float* __restrict__ partial) {
    const int b     = blockIdx.x;   // 0..31
    const int chunk = blockIdx.y;   // 0..31
    const int tid   = threadIdx.x;

    const floatx4* xb = reinterpret_cast<const floatx4*>(xf) + (size_t)b * D4;
    const size_t strideI = (size_t)BATCH * D4;   // float4 stride between maps

    float acc[NPAIR];
#pragma unroll
    for (int k = 0; k < NPAIR; ++k) acc[k] = 0.0f;

#pragma unroll 1
    for (int j = chunk * TPB + tid; j < D4; j += JSTRIDE) {
        floatx4 v[NMAPS];
#pragma unroll
        for (int i = 0; i < NMAPS; ++i)
            v[i] = __builtin_nontemporal_load(&xb[(size_t)i * strideI + j]);
        int k = 0;
#pragma unroll
        for (int i = 0; i < NMAPS; ++i) {
#pragma unroll
            for (int jj = i; jj < NMAPS; ++jj) {
                acc[k] += v[i].x * v[jj].x + v[i].y * v[jj].y +
                          v[i].z * v[jj].z + v[i].w * v[jj].w;
                ++k;
            }
        }
    }

    // wave shuffle reduce, then cross-wave LDS reduce
    const int lane = tid & 63;
    const int wave = tid >> 6;
    __shared__ float red[TPB / 64][NPAIR];
#pragma unroll
    for (int k = 0; k < NPAIR; ++k) {
        float s = acc[k];
#pragma unroll
        for (int off = 32; off > 0; off >>= 1) s += __shfl_down(s, off, 64);
        if (lane == 0) red[wave][k] = s;
    }
    __syncthreads();
    if (tid < NPAIR) {
        // layout: partial[(b*36+k)*CHUNKS + chunk] -> finalize reads float4
        partial[((size_t)b * NPAIR + tid) * CHUNKS + chunk] =
            red[0][tid] + red[1][tid] + red[2][tid] + red[3][tid];
    }
}

// Kernel 2: sum partials over chunks, then cosine epilogue. One block.
__global__ __launch_bounds__(256) void finalize_kernel(const float* __restrict__ partial,
                                                       float* __restrict__ out) {
    const int tid = threadIdx.x;
    __shared__ float dots_s[BATCH * NPAIR];   // [b][k]
    __shared__ float norms[BATCH][NMAPS];

    for (int item = tid; item < BATCH * NPAIR; item += 256) {
        const float4* p = reinterpret_cast<const float4*>(partial + (size_t)item * CHUNKS);
        float s = 0.0f;
#pragma unroll
        for (int c = 0; c < CHUNKS / 4; ++c) {
            float4 t = p[c];
            s += t.x + t.y + t.z + t.w;
        }
        dots_s[item] = s;
    }
    __syncthreads();
    {
        int bb = tid >> 3, i = tid & 7;             // 256 = 32*8
        int diag = 8 * i - (i * (i - 1)) / 2;
        norms[bb][i] = sqrtf(dots_s[bb * NPAIR + diag]);
    }
    __syncthreads();

    float sum = 0.0f;
    for (int item = tid; item < 28 * BATCH; item += 256) {
        int p = item >> 5;   // pair 0..27
        int bb = item & 31;
        int i = 0, rem = p;
        while (rem >= 7 - i) { rem -= 7 - i; ++i; }
        int j = i + 1 + rem;
        int k = 8 * i - (i * (i - 1)) / 2 + (j - i);
        float d   = fabsf(dots_s[bb * NPAIR + k]);
        float den = fmaxf(norms[bb][i] * norms[bb][j], 1e-8f);
        sum += d / den;
    }

    const int lane = tid & 63, wave = tid >> 6;
    __shared__ float red2[4];
#pragma unroll
    for (int off = 32; off > 0; off >>= 1) sum += __shfl_down(sum, off, 64);
    if (lane == 0) red2[wave] = sum;
    __syncthreads();
    if (tid == 0)
        out[0] = (red2[0] + red2[1] + red2[2] + red2[3]) / (28.0f * BATCH);
}

extern "C" void kernel_launch(void* const* d_in, const int* in_sizes, int n_in,
                              void* d_out, int out_size, void* d_ws, size_t ws_size,
                              hipStream_t stream) {
    const float* x       = (const float*)d_in[0];
    float*       out     = (float*)d_out;
    float*       partial = (float*)d_ws;   // BATCH*NPAIR*CHUNKS floats = 147 KB

    dim3 grid(BATCH, CHUNKS);
    gram_kernel<<<grid, TPB, 0, stream>>>(x, partial);
    finalize_kernel<<<1, 256, 0, stream>>>(partial, out);
}